// Round 1
// baseline (425.439 us; speedup 1.0000x reference)
//
#include <hip/hip_runtime.h>
#include <hip/hip_bf16.h>

// Reference: out = copy of signal (8192 x 8192 fp32). Pure D2D memcpy.
// 256 MiB read + 256 MiB write => roofline ~85 us at 6.3 TB/s achievable.
//
// hipMemcpyAsync(DeviceToDevice, stream) is graph-capture-safe (becomes a
// memcpy node) and uses the runtime's tuned copy path. A fallback grid-stride
// float4 kernel is provided but unused unless the memcpy path ever
// underperforms (m13: float4 copy kernel = 6.29 TB/s, 79% of peak).

__global__ void copy_f4_kernel(const float4* __restrict__ src,
                               float4* __restrict__ dst, long n4) {
    long i = (long)blockIdx.x * blockDim.x + threadIdx.x;
    long stride = (long)gridDim.x * blockDim.x;
    for (; i < n4; i += stride) {
        dst[i] = src[i];
    }
}

extern "C" void kernel_launch(void* const* d_in, const int* in_sizes, int n_in,
                              void* d_out, int out_size, void* d_ws, size_t ws_size,
                              hipStream_t stream) {
    const float* src = (const float*)d_in[0];
    float* dst = (float*)d_out;
    size_t bytes = (size_t)out_size * sizeof(float);  // 8192*8192*4 = 256 MiB
    hipMemcpyAsync(dst, src, bytes, hipMemcpyDeviceToDevice, stream);
}